// Round 10
// baseline (261.270 us; speedup 1.0000x reference)
//
#include <hip/hip_runtime.h>
#include <cstdint>
#include <cstddef>

#define N_TOT   147456      // 9*128*128
#define K_PRE   6000
#define K_POST  300
#define CAP     32768       // candidate cap (expected ~9.2K)
#define MW      188         // 6016 bits per mask row -> 188 u32 words
#define ROWS_PAD 6016
#define NCHUNK  94
#define CT      128         // k_mask columns per tile
#define ROWB    24
#define COLB    47          // ceil(6000/128)
#define G       16          // candidates ranked per wave

__constant__ float c_sizes[9] = {4.f,8.f,12.f,16.f,24.f,32.f,48.f,64.f,96.f};

// Bit-exact replication of reference box math (anchor + delta, clip).
__device__ __forceinline__ void compute_box(int idx, const float* __restrict__ deltas,
                                            float& px1, float& py1, float& pw, float& ph) {
    int a   = idx >> 14;
    int rem = idx & 16383;
    int h   = rem >> 7;
    int w   = rem & 127;
    float s    = c_sizes[a];
    float half = s * 0.5f;
    const float4 d = *(const float4*)(deltas + (size_t)a * 65536 + (size_t)rem * 4);
    float b0 = (((float)h + 0.5f) - half) + d.x;
    float b1 = (((float)w + 0.5f) - half) + d.y;
    float b2 = s + d.z;
    float b3 = s + d.w;
    b0 = fmaxf(b0, 0.0f); b1 = fmaxf(b1, 0.0f);
    b2 = fmaxf(b2, 0.0f); b3 = fmaxf(b3, 0.0f);
    float x1 = b0, y1 = b1;
    float x2 = b0 + b2, y2 = b1 + b3;
    x1 = fminf(x1, 128.0f); y1 = fminf(y1, 128.0f);
    x2 = fminf(x2, 128.0f); y2 = fminf(y2, 128.0f);
    px1 = x1; py1 = y1; pw = x2 - x1; ph = y2 - y1;
}

__device__ __forceinline__ uint32_t waveReduceSum(uint32_t v) {
    #pragma unroll
    for (int o = 32; o > 0; o >>= 1) v += __shfl_xor(v, o, 64);
    return v;
}

__global__ void k_keys_hist(const float* __restrict__ scores, const float* __restrict__ deltas,
                            uint32_t* __restrict__ keys, uint32_t* __restrict__ hist) {
    __shared__ uint32_t lh[4096];
    for (int i = threadIdx.x; i < 4096; i += 256) lh[i] = 0u;
    __syncthreads();
    int idx = blockIdx.x * 256 + threadIdx.x;
    float px1, py1, pw, ph;
    compute_box(idx, deltas, px1, py1, pw, ph);
    bool keep = (pw >= 3.0f) && (ph >= 3.0f);
    float sc = scores[idx];
    uint32_t key = keep ? __float_as_uint(sc) : 0u;
    keys[idx] = key;
    atomicAdd(&lh[key >> 20], 1u);
    __syncthreads();
    for (int i = threadIdx.x; i < 4096; i += 256) {
        uint32_t v = lh[i];
        if (v) atomicAdd(&hist[i], v);
    }
}

// per-block findbin (parallel suffix-scan, no serial walk) + compact slice
__global__ void k_findbin_compact(const uint32_t* __restrict__ hist,
                                  const uint32_t* __restrict__ keys,
                                  uint64_t* __restrict__ cand, uint32_t* counter) {
    __shared__ uint32_t lh[4096];
    __shared__ uint32_t seg[256];
    __shared__ uint32_t bsh;
    for (int i = threadIdx.x; i < 4096; i += 256) lh[i] = hist[i];
    __syncthreads();
    uint32_t s = 0;
    #pragma unroll
    for (int q = 0; q < 16; q++) s += lh[threadIdx.x * 16 + q];
    seg[threadIdx.x] = s;
    __syncthreads();
    // suffix-sum scan (Hillis-Steele, 8 steps): seg[t] = sum of segments >= t
    for (int off = 1; off < 256; off <<= 1) {
        uint32_t v = seg[threadIdx.x];
        if (threadIdx.x + off < 256) v += seg[threadIdx.x + off];
        __syncthreads();
        seg[threadIdx.x] = v;
        __syncthreads();
    }
    uint32_t St  = seg[threadIdx.x];
    uint32_t St1 = (threadIdx.x < 255) ? seg[threadIdx.x + 1] : 0u;
    if (St >= K_PRE && St1 < K_PRE) {     // exactly one thread (when total >= K_PRE)
        uint32_t c2 = St1;
        uint32_t bstar = 0u;
        for (int q = 15; q >= 0; q--) {
            c2 += lh[threadIdx.x * 16 + q];
            if (c2 >= K_PRE) { bstar = (uint32_t)(threadIdx.x * 16 + q); break; }
        }
        bsh = bstar;
    }
    if (threadIdx.x == 0 && seg[0] < K_PRE) bsh = 0u;   // degenerate guard
    __syncthreads();
    uint32_t bstar = bsh;
    int idx = blockIdx.x * 256 + threadIdx.x;
    uint32_t key = keys[idx];
    if ((key >> 20) >= bstar) {
        uint32_t pos = atomicAdd(counter, 1u);
        if (pos < CAP) cand[pos] = ((uint64_t)key << 32) | (uint32_t)(~(uint32_t)idx);
    }
}

// rank-by-count (exact top_k order: score desc, idx asc) fused with props/ykey
// generation. G=16 candidates per wave: ~40 VALU ops per loaded key hides L2
// latency (R9: G=4 was latency-bound at 46 us, VALUBusy 11%).
__global__ void k_rank_props(const uint64_t* __restrict__ cand, const uint32_t* __restrict__ meta,
                             const float* __restrict__ deltas,
                             float4* __restrict__ P, uint64_t* __restrict__ yk) {
    uint32_t C = meta[1];
    if (C > CAP) C = CAP;
    int lane = threadIdx.x & 63;
    uint32_t wid = (uint32_t)(blockIdx.x * 4 + (threadIdx.x >> 6));
    uint32_t stride = gridDim.x * 4;
    uint32_t nGroups = (C + G - 1) / G;
    for (uint32_t g = wid; g < nGroups; g += stride) {
        uint32_t b = g * G;
        uint64_t m[G];
        uint32_t cnt[G];
        #pragma unroll
        for (int q = 0; q < G; q++) {
            m[q] = (b + q < C) ? cand[b + q] : ~0ull;
            cnt[q] = 0u;
        }
        for (uint32_t j = lane; j < C; j += 64) {
            uint64_t k = cand[j];
            #pragma unroll
            for (int q = 0; q < G; q++) cnt[q] += (k > m[q]) ? 1u : 0u;
        }
        #pragma unroll
        for (int q = 0; q < G; q++) cnt[q] = waveReduceSum(cnt[q]);
        if (lane == 0) {
            #pragma unroll
            for (int q = 0; q < G; q++) {
                if (b + q < C && cnt[q] < K_PRE) {
                    uint32_t r = cnt[q];
                    int idx = (int)(~((uint32_t)m[q]));
                    float px1, py1, pw, ph;
                    compute_box(idx, deltas, px1, py1, pw, ph);
                    P[r] = make_float4(px1, py1, pw, ph);
                    float y2 = py1 + ph;
                    yk[r] = ((uint64_t)__float_as_uint(y2) << 32) | (uint32_t)(~r);
                }
            }
        }
    }
}

// stable y2-desc rank (G=16/wave); writes y2-ordered props OP, corners Q, and
// the exact div-free boundary: pred( round(d/area) >= 0.7f ) <=> d >= Bnd.
// M = 0.7f - 2^-25; M*(double)area exact; Bnd = smallest fp32 > M*area.
__global__ void k_rank_y2(const uint64_t* __restrict__ ykey, const float4* __restrict__ P,
                          float4* __restrict__ OP, float4* __restrict__ Q, float* __restrict__ Bnd) {
    int lane = threadIdx.x & 63;
    uint32_t wid = (uint32_t)(blockIdx.x * 4 + (threadIdx.x >> 6));
    uint32_t stride = gridDim.x * 4;
    uint32_t nGroups = K_PRE / G;     // 375
    for (uint32_t g = wid; g < nGroups; g += stride) {
        uint32_t b = g * G;
        uint64_t m[G];
        uint32_t cnt[G];
        #pragma unroll
        for (int q = 0; q < G; q++) {
            m[q] = ykey[b + q];
            cnt[q] = 0u;
        }
        for (uint32_t j = lane; j < K_PRE; j += 64) {
            uint64_t k = ykey[j];
            #pragma unroll
            for (int q = 0; q < G; q++) cnt[q] += (k > m[q]) ? 1u : 0u;
        }
        #pragma unroll
        for (int q = 0; q < G; q++) cnt[q] = waveReduceSum(cnt[q]);
        if (lane == 0) {
            const double Mc = (double)0.7f - 0x1.0p-25;
            #pragma unroll
            for (int q = 0; q < G; q++) {
                float4 p = P[b + q];
                uint32_t r = cnt[q];
                OP[r] = p;
                float x1 = p.x, y1 = p.y;
                float x2 = x1 + p.z, y2 = y1 + p.w;
                float area = fmaxf((x2 - x1) * (y2 - y1), 1e-6f);
                Q[r] = make_float4(x1, y1, x2, y2);
                double c = Mc * (double)area;       // exact
                float Bf = (float)c;
                if (!((double)Bf > c)) Bf = __int_as_float(__float_as_int(Bf) + 1);
                Bnd[r] = Bf;
            }
        }
    }
}

// suppression bitmask, tiled: lanes = rows, columns LDS-broadcast; div-free.
// CT=128 -> 1128 blocks (~4.4/CU) for latency hiding.
__global__ void __launch_bounds__(256) k_mask(const float4* __restrict__ Q,
                                              const float* __restrict__ Bnd,
                                              uint32_t* __restrict__ mask) {
    __shared__ float4 qs[CT];
    __shared__ float  bs[CT];
    int i  = blockIdx.x * 256 + threadIdx.x;     // row
    int c0 = blockIdx.y * CT;                    // first column of tile
    int ncols = min(CT, K_PRE - c0);
    bool rowok = (i < K_PRE);
    float4 qi = rowok ? Q[i] : make_float4(0.f, 0.f, 0.f, 0.f);
    for (int j = threadIdx.x; j < ncols; j += 256) {
        qs[j] = Q[c0 + j];
        bs[j] = Bnd[c0 + j];
    }
    __syncthreads();
    int nw = (ncols + 31) >> 5;
    for (int w = 0; w < nw; w++) {
        uint32_t bits = 0u;
        int jb = w * 32;
        int jn = min(32, ncols - jb);
        #pragma unroll 8
        for (int b = 0; b < jn; b++) {
            int j = jb + b;
            float4 qj = qs[j];
            float iw = fminf(qi.z, qj.z) - fmaxf(qi.x, qj.x) + 1.0f;
            iw = fmaxf(iw, 0.0f);
            float ih = fminf(qi.w, qj.w) - fmaxf(qi.y, qj.y) + 1.0f;
            ih = fmaxf(ih, 0.0f);
            float d = iw * ih;
            bits |= (d >= bs[j]) ? (1u << b) : 0u;
        }
        if (rowok) {
            int gj = c0 + jb;
            uint32_t selfo = (uint32_t)(i - gj);
            if (selfo < 32u) bits &= ~(1u << selfo);     // j == i excluded
            mask[(size_t)i * MW + (gj >> 5)] = bits;
        }
    }
}

// Serial active scan + final validity + emit, single block.
// Decide: active(i) = no earlier active k with mask[k][i]; leader iteration
// over uniform work mask, #iters == #survivors. OR phase: active rows of this
// chunk ORed into ALL 188 rem words -> at end rem = union over active rows of
// their mask rows; final valid = activeBits & ~rem (covers backward kills).
__global__ void __launch_bounds__(256) k_scan(const uint32_t* __restrict__ mask,
                                              const float4* __restrict__ OP,
                                              float* __restrict__ out) {
    __shared__ uint32_t rem[MW];
    __shared__ uint32_t sidx[64];
    __shared__ uint32_t svL[MW];
    __shared__ uint32_t nsSh;
    __shared__ uint32_t pref[MW];
    int tid = threadIdx.x;
    for (int i = tid; i < MW; i += 256) rem[i] = 0u;
    for (int i = tid; i < K_POST * 4; i += 256) out[i] = 0.0f;
    __syncthreads();
    uint2 mr = make_uint2(0u, 0u);
    if (tid < 64) mr = *(const uint2*)(mask + (size_t)tid * MW);   // chunk 0 rows
    for (int c = 0; c < NCHUNK; c++) {
        int base = c * 64;
        int rows = min(64, K_PRE - base);
        if (tid < 64) {
            uint64_t v = ~(((uint64_t)rem[2 * c + 1] << 32) | (uint64_t)rem[2 * c]);
            if (rows < 64) v &= ((1ull << rows) - 1ull);
            uint64_t work = v, surv = 0ull;
            while (work) {                      // leader iteration
                int k = __ffsll((unsigned long long)work) - 1;
                surv |= 1ull << k;
                uint64_t rowk =
                    ((uint64_t)(uint32_t)__builtin_amdgcn_readlane((int)mr.y, k) << 32)
                  |  (uint64_t)(uint32_t)__builtin_amdgcn_readlane((int)mr.x, k);
                work &= ~rowk;
                work &= ~(1ull << k);
            }
            uint32_t ns = (uint32_t)__popcll(surv);
            if (tid == 0) {
                svL[2 * c]     = (uint32_t)surv;
                svL[2 * c + 1] = (uint32_t)(surv >> 32);
                nsSh = ns;
            }
            if ((surv >> tid) & 1ull) {
                uint32_t pr = __popcll(surv & ((1ull << tid) - 1ull));
                sidx[pr] = (uint32_t)(base + tid);
            }
            if (surv) {             // pad sidx to x16 with first survivor (OR-idempotent)
                uint32_t nsPad = (ns + 15u) & ~15u;
                uint32_t first = (uint32_t)base +
                                 (uint32_t)(__ffsll((unsigned long long)surv) - 1);
                if ((uint32_t)tid >= ns && (uint32_t)tid < nsPad) sidx[tid] = first;
            }
            if (c + 1 < NCHUNK)     // prefetch next chunk rows (overlaps OR phase)
                mr = *(const uint2*)(mask + (size_t)(base + 64 + tid) * MW + 2 * (c + 1));
        }
        __syncthreads();
        int w = tid - 64;
        if (w >= 0 && w < MW) {
            uint32_t nsPad = (nsSh + 15u) & ~15u;
            uint32_t acc = rem[w];
            for (uint32_t t2 = 0; t2 < nsPad; t2 += 16) {
                uint32_t r[16];
                #pragma unroll
                for (int q = 0; q < 16; q++)
                    r[q] = mask[(size_t)sidx[t2 + q] * MW + w];
                uint32_t o = 0u;
                #pragma unroll
                for (int q = 0; q < 16; q++) o |= r[q];
                acc |= o;
            }
            rem[w] = acc;
        }
        __syncthreads();
    }
    // final validity + emit first 300 (tail already zeroed above)
    if (tid < MW) {
        uint32_t vv = svL[tid] & ~rem[tid];
        if (tid == MW - 1) vv &= 0xFFFFu;
        rem[tid] = vv;
    }
    __syncthreads();
    if (tid == 0) {
        uint32_t run = 0;
        for (int w2 = 0; w2 < MW; w2++) { pref[w2] = run; run += (uint32_t)__popc(rem[w2]); }
    }
    __syncthreads();
    if (tid < MW) {
        uint32_t b = rem[tid];
        uint32_t r = pref[tid];
        int basebit = tid * 32;
        while (b && r < K_POST) {
            int bit = __ffs(b) - 1;
            b &= b - 1u;
            float4 pp = OP[basebit + bit];
            *(float4*)(out + (size_t)r * 4) = pp;
            r++;
        }
    }
}

extern "C" void kernel_launch(void* const* d_in, const int* in_sizes, int n_in,
                              void* d_out, int out_size, void* d_ws, size_t ws_size,
                              hipStream_t stream) {
    (void)in_sizes; (void)n_in; (void)out_size; (void)ws_size;
    const float* scores = (const float*)d_in[0];
    const float* deltas = (const float*)d_in[1];
    float* out = (float*)d_out;

    char* ws = (char*)d_ws;
    size_t off = 0;
    auto alloc = [&](size_t bytes) -> void* {
        void* p = ws + off;
        off += (bytes + 255) & ~(size_t)255;
        return p;
    };
    uint32_t* hist  = (uint32_t*)alloc(4096 * 4);   // hist+meta contiguous: one memset
    uint32_t* meta  = (uint32_t*)alloc(64);
    uint32_t* keys  = (uint32_t*)alloc((size_t)N_TOT * 4);
    uint64_t* cand  = (uint64_t*)alloc((size_t)CAP * 8);
    float4*   P     = (float4*)alloc((size_t)K_PRE * 16);
    uint64_t* yk    = (uint64_t*)alloc((size_t)K_PRE * 8);
    float4*   OP    = (float4*)alloc((size_t)K_PRE * 16);
    float4*   Q     = (float4*)alloc((size_t)K_PRE * 16);
    float*    Bnd   = (float*)alloc((size_t)K_PRE * 4);
    uint32_t* mask  = (uint32_t*)alloc((size_t)ROWS_PAD * MW * 4);   // ~4.5 MB

    hipMemsetAsync(hist, 0, 4096 * 4 + 256, stream);   // hist + meta
    k_keys_hist<<<N_TOT / 256, 256, 0, stream>>>(scores, deltas, keys, hist);
    k_findbin_compact<<<N_TOT / 256, 256, 0, stream>>>(hist, keys, cand, meta + 1);
    k_rank_props<<<1024, 256, 0, stream>>>(cand, meta, deltas, P, yk);
    k_rank_y2<<<375, 256, 0, stream>>>(yk, P, OP, Q, Bnd);
    k_mask<<<dim3(ROWB, COLB), 256, 0, stream>>>(Q, Bnd, mask);
    k_scan<<<1, 256, 0, stream>>>(mask, OP, out);
}

// Round 11
// 189.332 us; speedup vs baseline: 1.3800x; 1.3800x over previous
//
#include <hip/hip_runtime.h>
#include <cstdint>
#include <cstddef>

#define N_TOT   147456      // 9*128*128
#define K_PRE   6000
#define K_POST  300
#define CAP     32768       // candidate cap (expected ~9.2K)
#define MW      188         // 6016 bits per mask row -> 188 u32 words
#define ROWS_PAD 6016
#define NCHUNK  94
#define CT      128         // k_mask columns per tile
#define ROWB    24
#define COLB    47          // ceil(6000/128)
#define G       16          // candidates ranked per BLOCK (R11: block-cooperative)

__constant__ float c_sizes[9] = {4.f,8.f,12.f,16.f,24.f,32.f,48.f,64.f,96.f};

// Bit-exact replication of reference box math (anchor + delta, clip).
__device__ __forceinline__ void compute_box(int idx, const float* __restrict__ deltas,
                                            float& px1, float& py1, float& pw, float& ph) {
    int a   = idx >> 14;
    int rem = idx & 16383;
    int h   = rem >> 7;
    int w   = rem & 127;
    float s    = c_sizes[a];
    float half = s * 0.5f;
    const float4 d = *(const float4*)(deltas + (size_t)a * 65536 + (size_t)rem * 4);
    float b0 = (((float)h + 0.5f) - half) + d.x;
    float b1 = (((float)w + 0.5f) - half) + d.y;
    float b2 = s + d.z;
    float b3 = s + d.w;
    b0 = fmaxf(b0, 0.0f); b1 = fmaxf(b1, 0.0f);
    b2 = fmaxf(b2, 0.0f); b3 = fmaxf(b3, 0.0f);
    float x1 = b0, y1 = b1;
    float x2 = b0 + b2, y2 = b1 + b3;
    x1 = fminf(x1, 128.0f); y1 = fminf(y1, 128.0f);
    x2 = fminf(x2, 128.0f); y2 = fminf(y2, 128.0f);
    px1 = x1; py1 = y1; pw = x2 - x1; ph = y2 - y1;
}

__device__ __forceinline__ uint32_t waveReduceSum(uint32_t v) {
    #pragma unroll
    for (int o = 32; o > 0; o >>= 1) v += __shfl_xor(v, o, 64);
    return v;
}

__global__ void k_keys_hist(const float* __restrict__ scores, const float* __restrict__ deltas,
                            uint32_t* __restrict__ keys, uint32_t* __restrict__ hist) {
    __shared__ uint32_t lh[4096];
    for (int i = threadIdx.x; i < 4096; i += 256) lh[i] = 0u;
    __syncthreads();
    int idx = blockIdx.x * 256 + threadIdx.x;
    float px1, py1, pw, ph;
    compute_box(idx, deltas, px1, py1, pw, ph);
    bool keep = (pw >= 3.0f) && (ph >= 3.0f);
    float sc = scores[idx];
    uint32_t key = keep ? __float_as_uint(sc) : 0u;
    keys[idx] = key;
    atomicAdd(&lh[key >> 20], 1u);
    __syncthreads();
    for (int i = threadIdx.x; i < 4096; i += 256) {
        uint32_t v = lh[i];
        if (v) atomicAdd(&hist[i], v);
    }
}

// per-block findbin (parallel suffix-scan, no serial walk) + compact slice
__global__ void k_findbin_compact(const uint32_t* __restrict__ hist,
                                  const uint32_t* __restrict__ keys,
                                  uint64_t* __restrict__ cand, uint32_t* counter) {
    __shared__ uint32_t lh[4096];
    __shared__ uint32_t seg[256];
    __shared__ uint32_t bsh;
    for (int i = threadIdx.x; i < 4096; i += 256) lh[i] = hist[i];
    __syncthreads();
    uint32_t s = 0;
    #pragma unroll
    for (int q = 0; q < 16; q++) s += lh[threadIdx.x * 16 + q];
    seg[threadIdx.x] = s;
    __syncthreads();
    // suffix-sum scan (Hillis-Steele, 8 steps): seg[t] = sum of segments >= t
    for (int off = 1; off < 256; off <<= 1) {
        uint32_t v = seg[threadIdx.x];
        if (threadIdx.x + off < 256) v += seg[threadIdx.x + off];
        __syncthreads();
        seg[threadIdx.x] = v;
        __syncthreads();
    }
    uint32_t St  = seg[threadIdx.x];
    uint32_t St1 = (threadIdx.x < 255) ? seg[threadIdx.x + 1] : 0u;
    if (St >= K_PRE && St1 < K_PRE) {     // exactly one thread (when total >= K_PRE)
        uint32_t c2 = St1;
        uint32_t bstar = 0u;
        for (int q = 15; q >= 0; q--) {
            c2 += lh[threadIdx.x * 16 + q];
            if (c2 >= K_PRE) { bstar = (uint32_t)(threadIdx.x * 16 + q); break; }
        }
        bsh = bstar;
    }
    if (threadIdx.x == 0 && seg[0] < K_PRE) bsh = 0u;   // degenerate guard
    __syncthreads();
    uint32_t bstar = bsh;
    int idx = blockIdx.x * 256 + threadIdx.x;
    uint32_t key = keys[idx];
    if ((key >> 20) >= bstar) {
        uint32_t pos = atomicAdd(counter, 1u);
        if (pos < CAP) cand[pos] = ((uint64_t)key << 32) | (uint32_t)(~(uint32_t)idx);
    }
}

// rank-by-count, block-cooperative: 16 candidates per BLOCK, 256 threads
// stride the array with 4 independent loads in flight (R10 lesson: per-wave
// G=16 killed TLP; this keeps ~2300 working waves AND ~400cyc compute/load-round).
__global__ void __launch_bounds__(256) k_rank_props(
        const uint64_t* __restrict__ cand, const uint32_t* __restrict__ meta,
        const float* __restrict__ deltas,
        float4* __restrict__ P, uint64_t* __restrict__ yk) {
    __shared__ uint32_t part[4][G];
    uint32_t C = meta[1];
    if (C > CAP) C = CAP;
    uint32_t nGroups = (C + G - 1) / G;
    int tid  = threadIdx.x;
    int wave = tid >> 6, lane = tid & 63;
    for (uint32_t g = blockIdx.x; g < nGroups; g += gridDim.x) {
        uint32_t b = g * G;
        uint64_t m[G];
        uint32_t cnt[G];
        #pragma unroll
        for (int q = 0; q < G; q++) {
            m[q] = (b + q < C) ? cand[b + q] : ~0ull;
            cnt[q] = 0u;
        }
        for (uint32_t j0 = 0; j0 < C; j0 += 1024) {
            uint32_t ja = j0 + tid, jb = ja + 256, jc = ja + 512, jd = ja + 768;
            uint64_t ka = (ja < C) ? cand[ja] : 0ull;   // 0 is never > m[q]
            uint64_t kb = (jb < C) ? cand[jb] : 0ull;
            uint64_t kc = (jc < C) ? cand[jc] : 0ull;
            uint64_t kd = (jd < C) ? cand[jd] : 0ull;
            #pragma unroll
            for (int q = 0; q < G; q++)
                cnt[q] += (uint32_t)(ka > m[q]) + (uint32_t)(kb > m[q])
                        + (uint32_t)(kc > m[q]) + (uint32_t)(kd > m[q]);
        }
        #pragma unroll
        for (int q = 0; q < G; q++) cnt[q] = waveReduceSum(cnt[q]);
        if (lane == 0) {
            #pragma unroll
            for (int q = 0; q < G; q++) part[wave][q] = cnt[q];
        }
        __syncthreads();
        if (tid < G && b + tid < C) {
            uint32_t r = part[0][tid] + part[1][tid] + part[2][tid] + part[3][tid];
            if (r < K_PRE) {
                int idx = (int)(~((uint32_t)cand[b + tid]));
                float px1, py1, pw, ph;
                compute_box(idx, deltas, px1, py1, pw, ph);
                P[r] = make_float4(px1, py1, pw, ph);
                float y2 = py1 + ph;
                yk[r] = ((uint64_t)__float_as_uint(y2) << 32) | (uint32_t)(~r);
            }
        }
        __syncthreads();
    }
}

// stable y2-desc rank, block-cooperative (16 rows/block, 375 blocks); parallel
// epilogue writes OP/Q and the exact div-free boundary:
// pred( round(d/area) >= 0.7f ) <=> d >= Bnd; M = 0.7f - 2^-25 (tie rounds to
// even predecessor => strict >); M*(double)area exact; Bnd = smallest fp32 > M*area.
__global__ void __launch_bounds__(256) k_rank_y2(
        const uint64_t* __restrict__ ykey, const float4* __restrict__ P,
        float4* __restrict__ OP, float4* __restrict__ Q, float* __restrict__ Bnd) {
    __shared__ uint32_t part[4][G];
    int tid  = threadIdx.x;
    int wave = tid >> 6, lane = tid & 63;
    uint32_t b = blockIdx.x * G;      // K_PRE/G = 375 blocks exactly
    uint64_t m[G];
    uint32_t cnt[G];
    #pragma unroll
    for (int q = 0; q < G; q++) {
        m[q] = ykey[b + q];
        cnt[q] = 0u;
    }
    for (uint32_t j0 = 0; j0 < K_PRE; j0 += 1024) {
        uint32_t ja = j0 + tid, jb = ja + 256, jc = ja + 512, jd = ja + 768;
        uint64_t ka = (ja < K_PRE) ? ykey[ja] : 0ull;
        uint64_t kb = (jb < K_PRE) ? ykey[jb] : 0ull;
        uint64_t kc = (jc < K_PRE) ? ykey[jc] : 0ull;
        uint64_t kd = (jd < K_PRE) ? ykey[jd] : 0ull;
        #pragma unroll
        for (int q = 0; q < G; q++)
            cnt[q] += (uint32_t)(ka > m[q]) + (uint32_t)(kb > m[q])
                    + (uint32_t)(kc > m[q]) + (uint32_t)(kd > m[q]);
    }
    #pragma unroll
    for (int q = 0; q < G; q++) cnt[q] = waveReduceSum(cnt[q]);
    if (lane == 0) {
        #pragma unroll
        for (int q = 0; q < G; q++) part[wave][q] = cnt[q];
    }
    __syncthreads();
    if (tid < G) {
        uint32_t r = part[0][tid] + part[1][tid] + part[2][tid] + part[3][tid];
        float4 p = P[b + tid];
        OP[r] = p;
        float x1 = p.x, y1 = p.y;
        float x2 = x1 + p.z, y2 = y1 + p.w;
        float area = fmaxf((x2 - x1) * (y2 - y1), 1e-6f);
        Q[r] = make_float4(x1, y1, x2, y2);
        const double Mc = (double)0.7f - 0x1.0p-25;
        double c = Mc * (double)area;       // exact
        float Bf = (float)c;
        if (!((double)Bf > c)) Bf = __int_as_float(__float_as_int(Bf) + 1);
        Bnd[r] = Bf;
    }
}

// suppression bitmask, tiled: lanes = rows, columns LDS-broadcast; div-free.
// CT=128 -> 1128 blocks (~4.4/CU) for latency hiding.
__global__ void __launch_bounds__(256) k_mask(const float4* __restrict__ Q,
                                              const float* __restrict__ Bnd,
                                              uint32_t* __restrict__ mask) {
    __shared__ float4 qs[CT];
    __shared__ float  bs[CT];
    int i  = blockIdx.x * 256 + threadIdx.x;     // row
    int c0 = blockIdx.y * CT;                    // first column of tile
    int ncols = min(CT, K_PRE - c0);
    bool rowok = (i < K_PRE);
    float4 qi = rowok ? Q[i] : make_float4(0.f, 0.f, 0.f, 0.f);
    for (int j = threadIdx.x; j < ncols; j += 256) {
        qs[j] = Q[c0 + j];
        bs[j] = Bnd[c0 + j];
    }
    __syncthreads();
    int nw = (ncols + 31) >> 5;
    for (int w = 0; w < nw; w++) {
        uint32_t bits = 0u;
        int jb = w * 32;
        int jn = min(32, ncols - jb);
        #pragma unroll 8
        for (int b = 0; b < jn; b++) {
            int j = jb + b;
            float4 qj = qs[j];
            float iw = fminf(qi.z, qj.z) - fmaxf(qi.x, qj.x) + 1.0f;
            iw = fmaxf(iw, 0.0f);
            float ih = fminf(qi.w, qj.w) - fmaxf(qi.y, qj.y) + 1.0f;
            ih = fmaxf(ih, 0.0f);
            float d = iw * ih;
            bits |= (d >= bs[j]) ? (1u << b) : 0u;
        }
        if (rowok) {
            int gj = c0 + jb;
            uint32_t selfo = (uint32_t)(i - gj);
            if (selfo < 32u) bits &= ~(1u << selfo);     // j == i excluded
            mask[(size_t)i * MW + (gj >> 5)] = bits;
        }
    }
}

// Serial active scan + final validity + emit, single block.
// Decide: active(i) = no earlier active k with mask[k][i]; leader iteration
// over uniform work mask, #iters == #survivors. OR phase: active rows of this
// chunk ORed into ALL 188 rem words -> at end rem = union over active rows of
// their mask rows; final valid = activeBits & ~rem (covers backward kills).
__global__ void __launch_bounds__(256) k_scan(const uint32_t* __restrict__ mask,
                                              const float4* __restrict__ OP,
                                              float* __restrict__ out) {
    __shared__ uint32_t rem[MW];
    __shared__ uint32_t sidx[64];
    __shared__ uint32_t svL[MW];
    __shared__ uint32_t nsSh;
    __shared__ uint32_t pref[MW];
    int tid = threadIdx.x;
    for (int i = tid; i < MW; i += 256) rem[i] = 0u;
    for (int i = tid; i < K_POST * 4; i += 256) out[i] = 0.0f;
    __syncthreads();
    uint2 mr = make_uint2(0u, 0u);
    if (tid < 64) mr = *(const uint2*)(mask + (size_t)tid * MW);   // chunk 0 rows
    for (int c = 0; c < NCHUNK; c++) {
        int base = c * 64;
        int rows = min(64, K_PRE - base);
        if (tid < 64) {
            uint64_t v = ~(((uint64_t)rem[2 * c + 1] << 32) | (uint64_t)rem[2 * c]);
            if (rows < 64) v &= ((1ull << rows) - 1ull);
            uint64_t work = v, surv = 0ull;
            while (work) {                      // leader iteration
                int k = __ffsll((unsigned long long)work) - 1;
                surv |= 1ull << k;
                uint64_t rowk =
                    ((uint64_t)(uint32_t)__builtin_amdgcn_readlane((int)mr.y, k) << 32)
                  |  (uint64_t)(uint32_t)__builtin_amdgcn_readlane((int)mr.x, k);
                work &= ~rowk;
                work &= ~(1ull << k);
            }
            uint32_t ns = (uint32_t)__popcll(surv);
            if (tid == 0) {
                svL[2 * c]     = (uint32_t)surv;
                svL[2 * c + 1] = (uint32_t)(surv >> 32);
                nsSh = ns;
            }
            if ((surv >> tid) & 1ull) {
                uint32_t pr = __popcll(surv & ((1ull << tid) - 1ull));
                sidx[pr] = (uint32_t)(base + tid);
            }
            if (surv) {             // pad sidx to x16 with first survivor (OR-idempotent)
                uint32_t nsPad = (ns + 15u) & ~15u;
                uint32_t first = (uint32_t)base +
                                 (uint32_t)(__ffsll((unsigned long long)surv) - 1);
                if ((uint32_t)tid >= ns && (uint32_t)tid < nsPad) sidx[tid] = first;
            }
            if (c + 1 < NCHUNK)     // prefetch next chunk rows (overlaps OR phase)
                mr = *(const uint2*)(mask + (size_t)(base + 64 + tid) * MW + 2 * (c + 1));
        }
        __syncthreads();
        int w = tid - 64;
        if (w >= 0 && w < MW) {
            uint32_t nsPad = (nsSh + 15u) & ~15u;
            uint32_t acc = rem[w];
            for (uint32_t t2 = 0; t2 < nsPad; t2 += 16) {
                uint32_t r[16];
                #pragma unroll
                for (int q = 0; q < 16; q++)
                    r[q] = mask[(size_t)sidx[t2 + q] * MW + w];
                uint32_t o = 0u;
                #pragma unroll
                for (int q = 0; q < 16; q++) o |= r[q];
                acc |= o;
            }
            rem[w] = acc;
        }
        __syncthreads();
    }
    // final validity + emit first 300 (tail already zeroed above)
    if (tid < MW) {
        uint32_t vv = svL[tid] & ~rem[tid];
        if (tid == MW - 1) vv &= 0xFFFFu;
        rem[tid] = vv;
    }
    __syncthreads();
    if (tid == 0) {
        uint32_t run = 0;
        for (int w2 = 0; w2 < MW; w2++) { pref[w2] = run; run += (uint32_t)__popc(rem[w2]); }
    }
    __syncthreads();
    if (tid < MW) {
        uint32_t b = rem[tid];
        uint32_t r = pref[tid];
        int basebit = tid * 32;
        while (b && r < K_POST) {
            int bit = __ffs(b) - 1;
            b &= b - 1u;
            float4 pp = OP[basebit + bit];
            *(float4*)(out + (size_t)r * 4) = pp;
            r++;
        }
    }
}

extern "C" void kernel_launch(void* const* d_in, const int* in_sizes, int n_in,
                              void* d_out, int out_size, void* d_ws, size_t ws_size,
                              hipStream_t stream) {
    (void)in_sizes; (void)n_in; (void)out_size; (void)ws_size;
    const float* scores = (const float*)d_in[0];
    const float* deltas = (const float*)d_in[1];
    float* out = (float*)d_out;

    char* ws = (char*)d_ws;
    size_t off = 0;
    auto alloc = [&](size_t bytes) -> void* {
        void* p = ws + off;
        off += (bytes + 255) & ~(size_t)255;
        return p;
    };
    uint32_t* hist  = (uint32_t*)alloc(4096 * 4);   // hist+meta contiguous: one memset
    uint32_t* meta  = (uint32_t*)alloc(64);
    uint32_t* keys  = (uint32_t*)alloc((size_t)N_TOT * 4);
    uint64_t* cand  = (uint64_t*)alloc((size_t)CAP * 8);
    float4*   P     = (float4*)alloc((size_t)K_PRE * 16);
    uint64_t* yk    = (uint64_t*)alloc((size_t)K_PRE * 8);
    float4*   OP    = (float4*)alloc((size_t)K_PRE * 16);
    float4*   Q     = (float4*)alloc((size_t)K_PRE * 16);
    float*    Bnd   = (float*)alloc((size_t)K_PRE * 4);
    uint32_t* mask  = (uint32_t*)alloc((size_t)ROWS_PAD * MW * 4);   // ~4.5 MB

    hipMemsetAsync(hist, 0, 4096 * 4 + 256, stream);   // hist + meta
    k_keys_hist<<<N_TOT / 256, 256, 0, stream>>>(scores, deltas, keys, hist);
    k_findbin_compact<<<N_TOT / 256, 256, 0, stream>>>(hist, keys, cand, meta + 1);
    k_rank_props<<<1024, 256, 0, stream>>>(cand, meta, deltas, P, yk);
    k_rank_y2<<<K_PRE / G, 256, 0, stream>>>(yk, P, OP, Q, Bnd);
    k_mask<<<dim3(ROWB, COLB), 256, 0, stream>>>(Q, Bnd, mask);
    k_scan<<<1, 256, 0, stream>>>(mask, OP, out);
}